// Round 2
// baseline (285.959 us; speedup 1.0000x reference)
//
#include <hip/hip_runtime.h>
#include <math.h>

#define D_    256
#define N_    1024
#define B_    8
#define H_    8
#define DV_   32
#define HID_  1024
#define ROWS_ (B_*N_)   // 8192

typedef __attribute__((ext_vector_type(8))) short s16x8;
typedef __attribute__((ext_vector_type(4))) float f32x4;

__device__ __forceinline__ unsigned short f2bf(float f) {
    unsigned u = __float_as_uint(f);
    unsigned r = (u + 0x7fffu + ((u >> 16) & 1u)) >> 16;
    return (unsigned short)r;
}

// ---------------------------------------------------------------- LayerNorm
__global__ __launch_bounds__(256) void k_ln(const float* __restrict__ x,
        const float* __restrict__ g, const float* __restrict__ b,
        float* __restrict__ pre) {
    int t = threadIdx.x;
    int lane = t & 63;
    int row = blockIdx.x * 4 + (t >> 6);
    const float4 v = ((const float4*)(x + row * D_))[lane];
    float s  = v.x + v.y + v.z + v.w;
    float sq = v.x*v.x + v.y*v.y + v.z*v.z + v.w*v.w;
    #pragma unroll
    for (int o = 32; o; o >>= 1) { s += __shfl_xor(s, o); sq += __shfl_xor(sq, o); }
    float m   = s * (1.0f / D_);
    float var = sq * (1.0f / D_) - m * m;
    float rs  = rsqrtf(var + 1e-5f);
    const float4 gv = ((const float4*)g)[lane];
    const float4 bv = ((const float4*)b)[lane];
    float4 o;
    o.x = (v.x - m) * rs * gv.x + bv.x;
    o.y = (v.y - m) * rs * gv.y + bv.y;
    o.z = (v.z - m) * rs * gv.z + bv.z;
    o.w = (v.w - m) * rs * gv.w + bv.w;
    ((float4*)(pre + row * D_))[lane] = o;
}

// ------------------------------------------------- generic fp32 tiled GEMM
__global__ __launch_bounds__(256) void k_gemm(const float* __restrict__ A,
        const float* __restrict__ Bm, const float* __restrict__ bias,
        float* __restrict__ C, int Ncols) {
    __shared__ float As[16][64];
    __shared__ float Bs[16][64];
    int t = threadIdx.x;
    int nBase = blockIdx.x * 64, rowBase = blockIdx.y * 64;
    int tx = t & 15, ty = t >> 4;
    int arow = t >> 2, ak = (t & 3) * 4;
    int bk = t >> 4, bn = (t & 15) * 4;
    float acc[4][4] = {};
    for (int kt = 0; kt < 256; kt += 16) {
        float4 av = *(const float4*)(A + (rowBase + arow) * 256 + kt + ak);
        As[ak+0][arow] = av.x; As[ak+1][arow] = av.y;
        As[ak+2][arow] = av.z; As[ak+3][arow] = av.w;
        float4 bv = make_float4(0.f, 0.f, 0.f, 0.f);
        if (nBase + bn < Ncols)
            bv = *(const float4*)(Bm + (kt + bk) * Ncols + nBase + bn);
        *(float4*)&Bs[bk][bn] = bv;
        __syncthreads();
        #pragma unroll
        for (int kk = 0; kk < 16; ++kk) {
            float4 a4 = *(const float4*)&As[kk][ty*4];
            float4 b4 = *(const float4*)&Bs[kk][tx*4];
            acc[0][0] += a4.x*b4.x; acc[0][1] += a4.x*b4.y; acc[0][2] += a4.x*b4.z; acc[0][3] += a4.x*b4.w;
            acc[1][0] += a4.y*b4.x; acc[1][1] += a4.y*b4.y; acc[1][2] += a4.y*b4.z; acc[1][3] += a4.y*b4.w;
            acc[2][0] += a4.z*b4.x; acc[2][1] += a4.z*b4.y; acc[2][2] += a4.z*b4.z; acc[2][3] += a4.z*b4.w;
            acc[3][0] += a4.w*b4.x; acc[3][1] += a4.w*b4.y; acc[3][2] += a4.w*b4.z; acc[3][3] += a4.w*b4.w;
        }
        __syncthreads();
    }
    int col = nBase + tx * 4;
    if (col < Ncols) {
        float4 bb = make_float4(0.f,0.f,0.f,0.f);
        if (bias) bb = *(const float4*)(bias + col);
        #pragma unroll
        for (int i = 0; i < 4; ++i) {
            float4 o;
            o.x = acc[i][0] + bb.x; o.y = acc[i][1] + bb.y;
            o.z = acc[i][2] + bb.z; o.w = acc[i][3] + bb.w;
            *(float4*)(C + (rowBase + ty*4 + i) * Ncols + col) = o;
        }
    }
}

// ------------------------------------------------------- scores argmax
__global__ __launch_bounds__(256) void k_argmax(const float* __restrict__ q,
        const float* __restrict__ kv, int* __restrict__ idx) {
    __shared__ float4 kt[128][8];
    __shared__ float cval[64][16];
    __shared__ int   cidx[64][16];
    int t = threadIdx.x;
    int itile = blockIdx.x, h = blockIdx.y, b = blockIdx.z;
    int ig = t & 15, slice = t >> 4;
    int i0 = itile * 64 + ig * 4;
    const float4* q4  = (const float4*)q;
    const float4* kv4 = (const float4*)kv;
    float4 qr[4][8];
    #pragma unroll
    for (int ii = 0; ii < 4; ++ii)
        #pragma unroll
        for (int d4 = 0; d4 < 8; ++d4)
            qr[ii][d4] = q4[(b * N_ + i0 + ii) * 8 + d4];
    float best[4] = {-1e30f, -1e30f, -1e30f, -1e30f};
    int   bj[4]   = {0, 0, 0, 0};
    for (int chunk = 0; chunk < 8; ++chunk) {
        int jb = chunk * 128;
        #pragma unroll
        for (int m2 = 0; m2 < 4; ++m2) {
            int u = t + m2 * 256;
            int j = u >> 3, d4 = u & 7;
            kt[j][d4 ^ ((j >> 3) & 7)] =
                kv4[(b * N_ + jb + j) * 128 + h * 8 + d4];
        }
        __syncthreads();
        #pragma unroll
        for (int jj = 0; jj < 8; ++jj) {
            int j = slice * 8 + jj;
            int sw = (j >> 3) & 7;
            float4 kk[8];
            #pragma unroll
            for (int d4 = 0; d4 < 8; ++d4) kk[d4] = kt[j][d4 ^ sw];
            int jg = jb + j;
            #pragma unroll
            for (int ii = 0; ii < 4; ++ii) {
                float s = 0.f;
                #pragma unroll
                for (int d4 = 0; d4 < 8; ++d4) {
                    s += qr[ii][d4].x * kk[d4].x;
                    s += qr[ii][d4].y * kk[d4].y;
                    s += qr[ii][d4].z * kk[d4].z;
                    s += qr[ii][d4].w * kk[d4].w;
                }
                if (s > best[ii]) { best[ii] = s; bj[ii] = jg; }
            }
        }
        __syncthreads();
    }
    #pragma unroll
    for (int ii = 0; ii < 4; ++ii) {
        cval[ig*4 + ii][slice] = best[ii];
        cidx[ig*4 + ii][slice] = bj[ii];
    }
    __syncthreads();
    if (t < 64) {
        float bv = cval[t][0]; int bi = cidx[t][0];
        #pragma unroll
        for (int s = 1; s < 16; ++s) {
            float v = cval[t][s]; int j2 = cidx[t][s];
            if (v > bv || (v == bv && j2 < bi)) { bv = v; bi = j2; }
        }
        idx[(b * H_ + h) * N_ + itile * 64 + t] = bi;
    }
}

// ------------------------------------------------- gather + LN(32) + head-sum
// produces u[8192][64] = [hsum(32), 8*res(32)]
__global__ __launch_bounds__(256) void k_hsum(const float* __restrict__ kv,
        const int* __restrict__ idx, const float* __restrict__ res,
        const float* __restrict__ g, const float* __restrict__ bb,
        float* __restrict__ u) {
    __shared__ float rel[32][8][33];
    int t = threadIdx.x;
    int rowBase = blockIdx.x * 32;
    int rw = t >> 3, h = t & 7;
    int bn = rowBase + rw;
    int b = bn >> 10, i = bn & 1023;
    int j = idx[(b * H_ + h) * N_ + i];
    const float4* src = (const float4*)kv + (b * N_ + j) * 128 + 64 + h * 8;
    float v[32];
    #pragma unroll
    for (int c = 0; c < 8; ++c) {
        float4 f = src[c];
        v[c*4+0] = f.x; v[c*4+1] = f.y; v[c*4+2] = f.z; v[c*4+3] = f.w;
    }
    float s = 0.f, sq = 0.f;
    #pragma unroll
    for (int d = 0; d < 32; ++d) { s += v[d]; sq += v[d]*v[d]; }
    float m = s * (1.f/32.f), var = sq * (1.f/32.f) - m * m;
    float rs = rsqrtf(var + 1e-5f);
    #pragma unroll
    for (int d = 0; d < 32; ++d)
        rel[rw][h][d] = (v[d] - m) * rs * g[d] + bb[d];
    __syncthreads();
    #pragma unroll
    for (int e = t; e < 1024; e += 256) {
        int r = e >> 5, d = e & 31;
        float acc = 0.f;
        #pragma unroll
        for (int hh = 0; hh < 8; ++hh) acc += rel[r][hh][d];
        u[(rowBase + r) * 64 + d]      = acc;
        u[(rowBase + r) * 64 + 32 + d] = 8.f * res[(rowBase + r) * 32 + d];
    }
}

// ------------------------------------------------- mid = gelu(u @ w_inner + 8*b_inner), bf16 out
__global__ __launch_bounds__(256) void k_mid(const float* __restrict__ u,
        const float* __restrict__ w_inner, const float* __restrict__ b_inner,
        unsigned short* __restrict__ mid) {
    __shared__ float us[16][64];
    __shared__ float wl[32][256];
    int t = threadIdx.x;
    int rowBase = blockIdx.x * 16;
    int colBase = blockIdx.y * 256;
    // stage u tile
    {
        int r = t >> 4, c4 = (t & 15) * 4;
        *(float4*)&us[r][c4] = *(const float4*)(u + (rowBase + r) * 64 + c4);
    }
    int r0 = (t >> 6) * 4;
    int c4 = (t & 63) * 4;
    float iacc[4][4] = {};
    for (int kh = 0; kh < 2; ++kh) {
        if (kh) __syncthreads();  // all done reading wl before restage
        #pragma unroll
        for (int e = t; e < 2048; e += 256) {
            int kr = e >> 6, cc = (e & 63) * 4;
            *(float4*)&wl[kr][cc] =
                *(const float4*)(w_inner + (kh * 32 + kr) * HID_ + colBase + cc);
        }
        __syncthreads();
        #pragma unroll
        for (int k = 0; k < 32; ++k) {
            float4 w4 = *(const float4*)&wl[k][c4];
            float a0 = us[r0+0][kh*32+k];
            float a1 = us[r0+1][kh*32+k];
            float a2 = us[r0+2][kh*32+k];
            float a3 = us[r0+3][kh*32+k];
            iacc[0][0] += a0*w4.x; iacc[0][1] += a0*w4.y; iacc[0][2] += a0*w4.z; iacc[0][3] += a0*w4.w;
            iacc[1][0] += a1*w4.x; iacc[1][1] += a1*w4.y; iacc[1][2] += a1*w4.z; iacc[1][3] += a1*w4.w;
            iacc[2][0] += a2*w4.x; iacc[2][1] += a2*w4.y; iacc[2][2] += a2*w4.z; iacc[2][3] += a2*w4.w;
            iacc[3][0] += a3*w4.x; iacc[3][1] += a3*w4.y; iacc[3][2] += a3*w4.z; iacc[3][3] += a3*w4.w;
        }
    }
    float4 bi4 = *(const float4*)(b_inner + colBase + c4);
    #pragma unroll
    for (int i = 0; i < 4; ++i) {
        float g0 = iacc[i][0] + 8.f*bi4.x;
        float g1 = iacc[i][1] + 8.f*bi4.y;
        float g2 = iacc[i][2] + 8.f*bi4.z;
        float g3 = iacc[i][3] + 8.f*bi4.w;
        g0 = 0.5f*g0*(1.f + erff(g0*0.70710678118f));
        g1 = 0.5f*g1*(1.f + erff(g1*0.70710678118f));
        g2 = 0.5f*g2*(1.f + erff(g2*0.70710678118f));
        g3 = 0.5f*g3*(1.f + erff(g3*0.70710678118f));
        ushort4 m4;
        m4.x = f2bf(g0); m4.y = f2bf(g1); m4.z = f2bf(g2); m4.w = f2bf(g3);
        *(ushort4*)(mid + (size_t)(rowBase + r0 + i) * HID_ + colBase + c4) = m4;
    }
}

// ------------------------------------------------- w_outer[1024][256] -> woT[256][1024] bf16
__global__ __launch_bounds__(256) void k_cvtB(const float* __restrict__ w_outer,
        unsigned short* __restrict__ woT) {
    __shared__ float t64[64][65];
    int t = threadIdx.x;
    int k0 = blockIdx.x * 64, c0 = blockIdx.y * 64;
    #pragma unroll
    for (int e = t; e < 4096; e += 256) {
        int r = e >> 6, c = e & 63;
        t64[r][c] = w_outer[(k0 + r) * 256 + c0 + c];
    }
    __syncthreads();
    #pragma unroll
    for (int e = t; e < 4096; e += 256) {
        int c = e >> 6, k = e & 63;
        woT[(size_t)(c0 + c) * 1024 + k0 + k] = f2bf(t64[k][c]);
    }
}

// ------------------------------------------------- out = mid @ w_outer + b_outer + x (MFMA bf16)
__global__ __launch_bounds__(256) void k_out(const unsigned short* __restrict__ mid,
        const unsigned short* __restrict__ woT, const float* __restrict__ b_outer,
        const float* __restrict__ x, float* __restrict__ out) {
    __shared__ __align__(16) unsigned short As[2][4096];
    __shared__ __align__(16) unsigned short Bs[2][4096];
    int t = threadIdx.x;
    int rowBase = blockIdx.x * 64, colBase = blockIdx.y * 64;
    int l = t & 63, w = t >> 6, wr = w >> 1, wc = w & 1;
    // staging slots: chunk e -> (row=e>>3, c=e&7), swizzled slot
    int r0 = t >> 3,        c0 = t & 7;
    int r1 = (t + 256) >> 3, c1 = t & 7;
    int s0 = (r0 * 8 + (c0 ^ (r0 & 7))) * 8;
    int s1 = (r1 * 8 + (c1 ^ (r1 & 7))) * 8;
    f32x4 acc00 = {0.f,0.f,0.f,0.f}, acc01 = acc00, acc10 = acc00, acc11 = acc00;
    int m = l & 15, g = l >> 4;
    int swm = m & 7;
    // --- tile 0 stage
    {
        uint4 va0 = *(const uint4*)(mid + (size_t)(rowBase + r0) * 1024 + c0 * 8);
        uint4 va1 = *(const uint4*)(mid + (size_t)(rowBase + r1) * 1024 + c1 * 8);
        uint4 vb0 = *(const uint4*)(woT + (size_t)(colBase + r0) * 1024 + c0 * 8);
        uint4 vb1 = *(const uint4*)(woT + (size_t)(colBase + r1) * 1024 + c1 * 8);
        *(uint4*)&As[0][s0] = va0; *(uint4*)&As[0][s1] = va1;
        *(uint4*)&Bs[0][s0] = vb0; *(uint4*)&Bs[0][s1] = vb1;
    }
    __syncthreads();
    int cur = 0;
    for (int kt = 0; kt < 16; ++kt) {
        uint4 va0, va1, vb0, vb1;
        bool pf = (kt + 1) < 16;
        if (pf) {
            int k0 = (kt + 1) * 64;
            va0 = *(const uint4*)(mid + (size_t)(rowBase + r0) * 1024 + k0 + c0 * 8);
            va1 = *(const uint4*)(mid + (size_t)(rowBase + r1) * 1024 + k0 + c1 * 8);
            vb0 = *(const uint4*)(woT + (size_t)(colBase + r0) * 1024 + k0 + c0 * 8);
            vb1 = *(const uint4*)(woT + (size_t)(colBase + r1) * 1024 + k0 + c1 * 8);
        }
        #pragma unroll
        for (int ks = 0; ks < 2; ++ks) {
            int kc = ks * 4 + g;
            int sc = kc ^ swm;
            s16x8 a0 = *(const s16x8*)&As[cur][((wr*32      + m) * 8 + sc) * 8];
            s16x8 a1 = *(const s16x8*)&As[cur][((wr*32 + 16 + m) * 8 + sc) * 8];
            s16x8 b0 = *(const s16x8*)&Bs[cur][((wc*32      + m) * 8 + sc) * 8];
            s16x8 b1 = *(const s16x8*)&Bs[cur][((wc*32 + 16 + m) * 8 + sc) * 8];
            acc00 = __builtin_amdgcn_mfma_f32_16x16x32_bf16(a0, b0, acc00, 0, 0, 0);
            acc01 = __builtin_amdgcn_mfma_f32_16x16x32_bf16(a0, b1, acc01, 0, 0, 0);
            acc10 = __builtin_amdgcn_mfma_f32_16x16x32_bf16(a1, b0, acc10, 0, 0, 0);
            acc11 = __builtin_amdgcn_mfma_f32_16x16x32_bf16(a1, b1, acc11, 0, 0, 0);
        }
        if (pf) {
            *(uint4*)&As[cur ^ 1][s0] = va0; *(uint4*)&As[cur ^ 1][s1] = va1;
            *(uint4*)&Bs[cur ^ 1][s0] = vb0; *(uint4*)&Bs[cur ^ 1][s1] = vb1;
        }
        __syncthreads();
        cur ^= 1;
    }
    // epilogue: C/D layout col=l&15, row=(l>>4)*4+reg
    #pragma unroll
    for (int fr = 0; fr < 2; ++fr) {
        #pragma unroll
        for (int fc = 0; fc < 2; ++fc) {
            f32x4 A = fr == 0 ? (fc == 0 ? acc00 : acc01)
                              : (fc == 0 ? acc10 : acc11);
            int col = colBase + wc * 32 + fc * 16 + m;
            float bo = b_outer[col];
            #pragma unroll
            for (int r = 0; r < 4; ++r) {
                int row = rowBase + wr * 32 + fr * 16 + g * 4 + r;
                out[(size_t)row * 256 + col] = A[r] + bo + x[(size_t)row * 256 + col];
            }
        }
    }
}

extern "C" void kernel_launch(void* const* d_in, const int* in_sizes, int n_in,
                              void* d_out, int out_size, void* d_ws, size_t ws_size,
                              hipStream_t stream) {
    const float* x        = (const float*)d_in[0];
    const float* w_q      = (const float*)d_in[1];
    const float* w_kv     = (const float*)d_in[2];
    const float* ln_out_g = (const float*)d_in[3];
    const float* ln_out_b = (const float*)d_in[4];
    const float* ln_rel_g = (const float*)d_in[5];
    const float* ln_rel_b = (const float*)d_in[6];
    const float* w_down   = (const float*)d_in[7];
    const float* b_down   = (const float*)d_in[8];
    const float* w_inner  = (const float*)d_in[9];
    const float* b_inner  = (const float*)d_in[10];
    const float* w_outer  = (const float*)d_in[11];
    const float* b_outer  = (const float*)d_in[12];
    float* out = (float*)d_out;

    float* ws     = (float*)d_ws;
    float* pre    = ws;                        // 2,097,152 f
    float* qbuf   = ws + 2097152;              //   262,144 f
    float* kvbuf  = ws + 2359296;              // 4,194,304 f (ends 6,553,600)
    float* resbuf = ws + 6553600;              //   262,144 f
    float* ubuf   = ws + 6815744;              //   524,288 f
    int*   idxbuf = (int*)(ws + 7340032);      //    65,536 i
    unsigned short* woT = (unsigned short*)(ws + 7405568);  // 262,144 us = 131,072 f
    // mid aliases pre/qbuf/front-of-kvbuf (all dead by k_mid time)
    unsigned short* mid = (unsigned short*)ws; // 8,388,608 us = 4,194,304 f

    k_ln<<<2048, 256, 0, stream>>>(x, ln_out_g, ln_out_b, pre);
    k_gemm<<<dim3(8, 128), 256, 0, stream>>>(pre, w_kv, nullptr, kvbuf, 512);
    k_gemm<<<dim3(1, 128), 256, 0, stream>>>(pre, w_q, nullptr, qbuf, 32);
    k_gemm<<<dim3(1, 128), 256, 0, stream>>>(x, w_down, b_down, resbuf, 32);
    k_argmax<<<dim3(16, 8, 8), 256, 0, stream>>>(qbuf, kvbuf, idxbuf);
    k_cvtB<<<dim3(16, 4), 256, 0, stream>>>(w_outer, woT);
    k_hsum<<<256, 256, 0, stream>>>(kvbuf, idxbuf, resbuf, ln_rel_g, ln_rel_b, ubuf);
    k_mid<<<dim3(512, 4), 256, 0, stream>>>(ubuf, w_inner, b_inner, mid);
    k_out<<<dim3(128, 4), 256, 0, stream>>>(mid, woT, b_outer, x, out);
}

// Round 3
// 196.626 us; speedup vs baseline: 1.4543x; 1.4543x over previous
//
#include <hip/hip_runtime.h>
#include <math.h>

#define D_    256
#define N_    1024
#define B_    8
#define H_    8
#define DV_   32
#define HID_  1024
#define ROWS_ (B_*N_)   // 8192

typedef __attribute__((ext_vector_type(8))) short s16x8;
typedef __attribute__((ext_vector_type(4))) float f32x4;

__device__ __forceinline__ unsigned short f2bf(float f) {
    unsigned u = __float_as_uint(f);
    unsigned r = (u + 0x7fffu + ((u >> 16) & 1u)) >> 16;
    return (unsigned short)r;
}

// fast erf (Abramowitz-Stegun 7.1.26, |err| < 1.5e-7)
__device__ __forceinline__ float erf_fast(float x) {
    float ax = fabsf(x);
    float t = 1.f / (1.f + 0.3275911f * ax);
    float y = ((((1.061405429f * t - 1.453152027f) * t + 1.421413741f) * t
                - 0.284496736f) * t + 0.254829592f) * t;
    float e = __expf(-ax * ax);
    float r = 1.f - y * e;
    return x < 0.f ? -r : r;
}
__device__ __forceinline__ float gelu(float v) {
    return 0.5f * v * (1.f + erf_fast(v * 0.70710678118f));
}

// ---------------------------------------------------------------- LayerNorm
__global__ __launch_bounds__(256) void k_ln(const float* __restrict__ x,
        const float* __restrict__ g, const float* __restrict__ b,
        float* __restrict__ pre) {
    int t = threadIdx.x;
    int lane = t & 63;
    int row = blockIdx.x * 4 + (t >> 6);
    const float4 v = ((const float4*)(x + row * D_))[lane];
    float s  = v.x + v.y + v.z + v.w;
    float sq = v.x*v.x + v.y*v.y + v.z*v.z + v.w*v.w;
    #pragma unroll
    for (int o = 32; o; o >>= 1) { s += __shfl_xor(s, o); sq += __shfl_xor(sq, o); }
    float m   = s * (1.0f / D_);
    float var = sq * (1.0f / D_) - m * m;
    float rs  = rsqrtf(var + 1e-5f);
    const float4 gv = ((const float4*)g)[lane];
    const float4 bv = ((const float4*)b)[lane];
    float4 o;
    o.x = (v.x - m) * rs * gv.x + bv.x;
    o.y = (v.y - m) * rs * gv.y + bv.y;
    o.z = (v.z - m) * rs * gv.z + bv.z;
    o.w = (v.w - m) * rs * gv.w + bv.w;
    ((float4*)(pre + row * D_))[lane] = o;
}

// ------------------------------------------------- generic fp32 tiled GEMM
__global__ __launch_bounds__(256) void k_gemm(const float* __restrict__ A,
        const float* __restrict__ Bm, const float* __restrict__ bias,
        float* __restrict__ C, int Ncols) {
    __shared__ float As[16][64];
    __shared__ float Bs[16][64];
    int t = threadIdx.x;
    int nBase = blockIdx.x * 64, rowBase = blockIdx.y * 64;
    int tx = t & 15, ty = t >> 4;
    int arow = t >> 2, ak = (t & 3) * 4;
    int bk = t >> 4, bn = (t & 15) * 4;
    float acc[4][4] = {};
    for (int kt = 0; kt < 256; kt += 16) {
        float4 av = *(const float4*)(A + (rowBase + arow) * 256 + kt + ak);
        As[ak+0][arow] = av.x; As[ak+1][arow] = av.y;
        As[ak+2][arow] = av.z; As[ak+3][arow] = av.w;
        float4 bv = make_float4(0.f, 0.f, 0.f, 0.f);
        if (nBase + bn < Ncols)
            bv = *(const float4*)(Bm + (kt + bk) * Ncols + nBase + bn);
        *(float4*)&Bs[bk][bn] = bv;
        __syncthreads();
        #pragma unroll
        for (int kk = 0; kk < 16; ++kk) {
            float4 a4 = *(const float4*)&As[kk][ty*4];
            float4 b4 = *(const float4*)&Bs[kk][tx*4];
            acc[0][0] += a4.x*b4.x; acc[0][1] += a4.x*b4.y; acc[0][2] += a4.x*b4.z; acc[0][3] += a4.x*b4.w;
            acc[1][0] += a4.y*b4.x; acc[1][1] += a4.y*b4.y; acc[1][2] += a4.y*b4.z; acc[1][3] += a4.y*b4.w;
            acc[2][0] += a4.z*b4.x; acc[2][1] += a4.z*b4.y; acc[2][2] += a4.z*b4.z; acc[2][3] += a4.z*b4.w;
            acc[3][0] += a4.w*b4.x; acc[3][1] += a4.w*b4.y; acc[3][2] += a4.w*b4.z; acc[3][3] += a4.w*b4.w;
        }
        __syncthreads();
    }
    int col = nBase + tx * 4;
    if (col < Ncols) {
        float4 bb = make_float4(0.f,0.f,0.f,0.f);
        if (bias) bb = *(const float4*)(bias + col);
        #pragma unroll
        for (int i = 0; i < 4; ++i) {
            float4 o;
            o.x = acc[i][0] + bb.x; o.y = acc[i][1] + bb.y;
            o.z = acc[i][2] + bb.z; o.w = acc[i][3] + bb.w;
            *(float4*)(C + (rowBase + ty*4 + i) * Ncols + col) = o;
        }
    }
}

// ------------------------------------------------------- scores argmax
__global__ __launch_bounds__(256) void k_argmax(const float* __restrict__ q,
        const float* __restrict__ kv, int* __restrict__ idx) {
    __shared__ float4 kt[128][8];
    __shared__ float cval[64][16];
    __shared__ int   cidx[64][16];
    int t = threadIdx.x;
    int itile = blockIdx.x, h = blockIdx.y, b = blockIdx.z;
    int ig = t & 15, slice = t >> 4;
    int i0 = itile * 64 + ig * 4;
    const float4* q4  = (const float4*)q;
    const float4* kv4 = (const float4*)kv;
    float4 qr[4][8];
    #pragma unroll
    for (int ii = 0; ii < 4; ++ii)
        #pragma unroll
        for (int d4 = 0; d4 < 8; ++d4)
            qr[ii][d4] = q4[(b * N_ + i0 + ii) * 8 + d4];
    float best[4] = {-1e30f, -1e30f, -1e30f, -1e30f};
    int   bj[4]   = {0, 0, 0, 0};
    for (int chunk = 0; chunk < 8; ++chunk) {
        int jb = chunk * 128;
        #pragma unroll
        for (int m2 = 0; m2 < 4; ++m2) {
            int u = t + m2 * 256;
            int j = u >> 3, d4 = u & 7;
            kt[j][d4 ^ ((j >> 3) & 7)] =
                kv4[(b * N_ + jb + j) * 128 + h * 8 + d4];
        }
        __syncthreads();
        #pragma unroll
        for (int jj = 0; jj < 8; ++jj) {
            int j = slice * 8 + jj;
            int sw = (j >> 3) & 7;
            float4 kk[8];
            #pragma unroll
            for (int d4 = 0; d4 < 8; ++d4) kk[d4] = kt[j][d4 ^ sw];
            int jg = jb + j;
            #pragma unroll
            for (int ii = 0; ii < 4; ++ii) {
                float s = 0.f;
                #pragma unroll
                for (int d4 = 0; d4 < 8; ++d4) {
                    s += qr[ii][d4].x * kk[d4].x;
                    s += qr[ii][d4].y * kk[d4].y;
                    s += qr[ii][d4].z * kk[d4].z;
                    s += qr[ii][d4].w * kk[d4].w;
                }
                if (s > best[ii]) { best[ii] = s; bj[ii] = jg; }
            }
        }
        __syncthreads();
    }
    #pragma unroll
    for (int ii = 0; ii < 4; ++ii) {
        cval[ig*4 + ii][slice] = best[ii];
        cidx[ig*4 + ii][slice] = bj[ii];
    }
    __syncthreads();
    if (t < 64) {
        float bv = cval[t][0]; int bi = cidx[t][0];
        #pragma unroll
        for (int s = 1; s < 16; ++s) {
            float v = cval[t][s]; int j2 = cidx[t][s];
            if (v > bv || (v == bv && j2 < bi)) { bv = v; bi = j2; }
        }
        idx[(b * H_ + h) * N_ + itile * 64 + t] = bi;
    }
}

// ------------------------------------------------- gather + LN(32) + head-sum
// produces u[8192][64] bf16 = [hsum(32), 8*res(32)]
__global__ __launch_bounds__(256) void k_hsum(const float* __restrict__ kv,
        const int* __restrict__ idx, const float* __restrict__ res,
        const float* __restrict__ g, const float* __restrict__ bb,
        unsigned short* __restrict__ u) {
    __shared__ float rel[32][8][33];
    int t = threadIdx.x;
    int rowBase = blockIdx.x * 32;
    int rw = t >> 3, h = t & 7;
    int bn = rowBase + rw;
    int b = bn >> 10, i = bn & 1023;
    int j = idx[(b * H_ + h) * N_ + i];
    const float4* src = (const float4*)kv + (b * N_ + j) * 128 + 64 + h * 8;
    float v[32];
    #pragma unroll
    for (int c = 0; c < 8; ++c) {
        float4 f = src[c];
        v[c*4+0] = f.x; v[c*4+1] = f.y; v[c*4+2] = f.z; v[c*4+3] = f.w;
    }
    float s = 0.f, sq = 0.f;
    #pragma unroll
    for (int d = 0; d < 32; ++d) { s += v[d]; sq += v[d]*v[d]; }
    float m = s * (1.f/32.f), var = sq * (1.f/32.f) - m * m;
    float rs = rsqrtf(var + 1e-5f);
    #pragma unroll
    for (int d = 0; d < 32; ++d)
        rel[rw][h][d] = (v[d] - m) * rs * g[d] + bb[d];
    __syncthreads();
    #pragma unroll
    for (int e = t; e < 1024; e += 256) {
        int r = e >> 5, d = e & 31;
        float acc = 0.f;
        #pragma unroll
        for (int hh = 0; hh < 8; ++hh) acc += rel[r][hh][d];
        u[(rowBase + r) * 64 + d]      = f2bf(acc);
        u[(rowBase + r) * 64 + 32 + d] = f2bf(8.f * res[(rowBase + r) * 32 + d]);
    }
}

// ------------------------------------------------- transpose + bf16 convert
// src[r][c] (srcCols wide) -> dst[c][r] (dstCols wide), 64x64 tiles
__global__ __launch_bounds__(256) void k_cvtT(const float* __restrict__ src,
        unsigned short* __restrict__ dst, int srcCols, int dstCols) {
    __shared__ float t64[64][65];
    int t = threadIdx.x;
    int r0 = blockIdx.x * 64, c0 = blockIdx.y * 64;
    #pragma unroll
    for (int e = t; e < 4096; e += 256) {
        int r = e >> 6, c = e & 63;
        t64[r][c] = src[(size_t)(r0 + r) * srcCols + c0 + c];
    }
    __syncthreads();
    #pragma unroll
    for (int e = t; e < 4096; e += 256) {
        int c = e >> 6, r = e & 63;
        dst[(size_t)(c0 + c) * dstCols + r0 + r] = f2bf(t64[r][c]);
    }
}

// ------------------------------------------------- mid = gelu(u @ w_inner + 8*b_inner)
// MFMA bf16: u[8192][64] bf16, wiT[1024][64] bf16 -> mid[8192][1024] bf16
__global__ __launch_bounds__(256) void k_mid(const unsigned short* __restrict__ u,
        const unsigned short* __restrict__ wiT, const float* __restrict__ b_inner,
        unsigned short* __restrict__ mid) {
    __shared__ __align__(16) unsigned short As[4096];
    __shared__ __align__(16) unsigned short Bs[4096];
    int t = threadIdx.x;
    int rowBase = blockIdx.x * 64, colBase = blockIdx.y * 64;
    int l = t & 63, w = t >> 6, wr = w >> 1, wc = w & 1;
    // stage: thread t loads row r, chunks cA, cA+1 (8 bf16 each)
    int r = t >> 2, cA = (t & 3) * 2;
    {
        uint4 a0 = *(const uint4*)(u   + (size_t)(rowBase + r) * 64 + cA * 8);
        uint4 a1 = *(const uint4*)(u   + (size_t)(rowBase + r) * 64 + cA * 8 + 8);
        uint4 b0 = *(const uint4*)(wiT + (size_t)(colBase + r) * 64 + cA * 8);
        uint4 b1 = *(const uint4*)(wiT + (size_t)(colBase + r) * 64 + cA * 8 + 8);
        *(uint4*)&As[(r * 8 + ( cA      ^ (r & 7))) * 8] = a0;
        *(uint4*)&As[(r * 8 + ((cA + 1) ^ (r & 7))) * 8] = a1;
        *(uint4*)&Bs[(r * 8 + ( cA      ^ (r & 7))) * 8] = b0;
        *(uint4*)&Bs[(r * 8 + ((cA + 1) ^ (r & 7))) * 8] = b1;
    }
    __syncthreads();
    f32x4 acc00 = {0.f,0.f,0.f,0.f}, acc01 = acc00, acc10 = acc00, acc11 = acc00;
    int m = l & 15, g = l >> 4;
    int swm = m & 7;
    #pragma unroll
    for (int ks = 0; ks < 2; ++ks) {
        int kc = ks * 4 + g;
        int sc = kc ^ swm;
        s16x8 a0 = *(const s16x8*)&As[((wr*32      + m) * 8 + sc) * 8];
        s16x8 a1 = *(const s16x8*)&As[((wr*32 + 16 + m) * 8 + sc) * 8];
        s16x8 b0 = *(const s16x8*)&Bs[((wc*32      + m) * 8 + sc) * 8];
        s16x8 b1 = *(const s16x8*)&Bs[((wc*32 + 16 + m) * 8 + sc) * 8];
        acc00 = __builtin_amdgcn_mfma_f32_16x16x32_bf16(a0, b0, acc00, 0, 0, 0);
        acc01 = __builtin_amdgcn_mfma_f32_16x16x32_bf16(a0, b1, acc01, 0, 0, 0);
        acc10 = __builtin_amdgcn_mfma_f32_16x16x32_bf16(a1, b0, acc10, 0, 0, 0);
        acc11 = __builtin_amdgcn_mfma_f32_16x16x32_bf16(a1, b1, acc11, 0, 0, 0);
    }
    // epilogue: col=l&15 (+ fc*16 + wc*32), row=(l>>4)*4+reg (+ fr*16 + wr*32)
    #pragma unroll
    for (int fr = 0; fr < 2; ++fr) {
        #pragma unroll
        for (int fc = 0; fc < 2; ++fc) {
            f32x4 A = fr == 0 ? (fc == 0 ? acc00 : acc01)
                              : (fc == 0 ? acc10 : acc11);
            int col = colBase + wc * 32 + fc * 16 + m;
            float bi = 8.f * b_inner[col];
            #pragma unroll
            for (int rr = 0; rr < 4; ++rr) {
                int row = rowBase + wr * 32 + fr * 16 + g * 4 + rr;
                mid[(size_t)row * HID_ + col] = f2bf(gelu(A[rr] + bi));
            }
        }
    }
}

// ------------------------------------------------- out = mid @ w_outer + b_outer + x (MFMA bf16)
__global__ __launch_bounds__(256) void k_out(const unsigned short* __restrict__ mid,
        const unsigned short* __restrict__ woT, const float* __restrict__ b_outer,
        const float* __restrict__ x, float* __restrict__ out) {
    __shared__ __align__(16) unsigned short As[2][4096];
    __shared__ __align__(16) unsigned short Bs[2][4096];
    int t = threadIdx.x;
    int rowBase = blockIdx.x * 64, colBase = blockIdx.y * 64;
    int l = t & 63, w = t >> 6, wr = w >> 1, wc = w & 1;
    int r0 = t >> 3,        c0 = t & 7;
    int r1 = (t + 256) >> 3, c1 = t & 7;
    int s0 = (r0 * 8 + (c0 ^ (r0 & 7))) * 8;
    int s1 = (r1 * 8 + (c1 ^ (r1 & 7))) * 8;
    f32x4 acc00 = {0.f,0.f,0.f,0.f}, acc01 = acc00, acc10 = acc00, acc11 = acc00;
    int m = l & 15, g = l >> 4;
    int swm = m & 7;
    {
        uint4 va0 = *(const uint4*)(mid + (size_t)(rowBase + r0) * 1024 + c0 * 8);
        uint4 va1 = *(const uint4*)(mid + (size_t)(rowBase + r1) * 1024 + c1 * 8);
        uint4 vb0 = *(const uint4*)(woT + (size_t)(colBase + r0) * 1024 + c0 * 8);
        uint4 vb1 = *(const uint4*)(woT + (size_t)(colBase + r1) * 1024 + c1 * 8);
        *(uint4*)&As[0][s0] = va0; *(uint4*)&As[0][s1] = va1;
        *(uint4*)&Bs[0][s0] = vb0; *(uint4*)&Bs[0][s1] = vb1;
    }
    __syncthreads();
    int cur = 0;
    for (int kt = 0; kt < 16; ++kt) {
        uint4 va0, va1, vb0, vb1;
        bool pf = (kt + 1) < 16;
        if (pf) {
            int k0 = (kt + 1) * 64;
            va0 = *(const uint4*)(mid + (size_t)(rowBase + r0) * 1024 + k0 + c0 * 8);
            va1 = *(const uint4*)(mid + (size_t)(rowBase + r1) * 1024 + k0 + c1 * 8);
            vb0 = *(const uint4*)(woT + (size_t)(colBase + r0) * 1024 + k0 + c0 * 8);
            vb1 = *(const uint4*)(woT + (size_t)(colBase + r1) * 1024 + k0 + c1 * 8);
        }
        #pragma unroll
        for (int ks = 0; ks < 2; ++ks) {
            int kc = ks * 4 + g;
            int sc = kc ^ swm;
            s16x8 a0 = *(const s16x8*)&As[cur][((wr*32      + m) * 8 + sc) * 8];
            s16x8 a1 = *(const s16x8*)&As[cur][((wr*32 + 16 + m) * 8 + sc) * 8];
            s16x8 b0 = *(const s16x8*)&Bs[cur][((wc*32      + m) * 8 + sc) * 8];
            s16x8 b1 = *(const s16x8*)&Bs[cur][((wc*32 + 16 + m) * 8 + sc) * 8];
            acc00 = __builtin_amdgcn_mfma_f32_16x16x32_bf16(a0, b0, acc00, 0, 0, 0);
            acc01 = __builtin_amdgcn_mfma_f32_16x16x32_bf16(a0, b1, acc01, 0, 0, 0);
            acc10 = __builtin_amdgcn_mfma_f32_16x16x32_bf16(a1, b0, acc10, 0, 0, 0);
            acc11 = __builtin_amdgcn_mfma_f32_16x16x32_bf16(a1, b1, acc11, 0, 0, 0);
        }
        if (pf) {
            *(uint4*)&As[cur ^ 1][s0] = va0; *(uint4*)&As[cur ^ 1][s1] = va1;
            *(uint4*)&Bs[cur ^ 1][s0] = vb0; *(uint4*)&Bs[cur ^ 1][s1] = vb1;
        }
        __syncthreads();
        cur ^= 1;
    }
    #pragma unroll
    for (int fr = 0; fr < 2; ++fr) {
        #pragma unroll
        for (int fc = 0; fc < 2; ++fc) {
            f32x4 A = fr == 0 ? (fc == 0 ? acc00 : acc01)
                              : (fc == 0 ? acc10 : acc11);
            int col = colBase + wc * 32 + fc * 16 + m;
            float bo = b_outer[col];
            #pragma unroll
            for (int rr = 0; rr < 4; ++rr) {
                int row = rowBase + wr * 32 + fr * 16 + g * 4 + rr;
                out[(size_t)row * 256 + col] = A[rr] + bo + x[(size_t)row * 256 + col];
            }
        }
    }
}

extern "C" void kernel_launch(void* const* d_in, const int* in_sizes, int n_in,
                              void* d_out, int out_size, void* d_ws, size_t ws_size,
                              hipStream_t stream) {
    const float* x        = (const float*)d_in[0];
    const float* w_q      = (const float*)d_in[1];
    const float* w_kv     = (const float*)d_in[2];
    const float* ln_out_g = (const float*)d_in[3];
    const float* ln_out_b = (const float*)d_in[4];
    const float* ln_rel_g = (const float*)d_in[5];
    const float* ln_rel_b = (const float*)d_in[6];
    const float* w_down   = (const float*)d_in[7];
    const float* b_down   = (const float*)d_in[8];
    const float* w_inner  = (const float*)d_in[9];
    const float* b_inner  = (const float*)d_in[10];
    const float* w_outer  = (const float*)d_in[11];
    const float* b_outer  = (const float*)d_in[12];
    float* out = (float*)d_out;

    float* ws     = (float*)d_ws;
    float* pre    = ws;                        // 2,097,152 f
    float* qbuf   = ws + 2097152;              //   262,144 f
    float* kvbuf  = ws + 2359296;              // 4,194,304 f -> 6,553,600
    float* resbuf = ws + 6553600;              //   262,144 f -> 6,815,744
    unsigned short* ubuf = (unsigned short*)(ws + 6815744);  // 524,288 us = 262,144 f -> 7,077,888
    int*   idxbuf = (int*)(ws + 7077888);      //    65,536 i -> 7,143,424
    unsigned short* woT = (unsigned short*)(ws + 7143424);   // 262,144 us -> 7,274,496
    unsigned short* wiT = (unsigned short*)(ws + 7274496);   //  65,536 us -> 7,307,264
    // mid aliases pre/qbuf/front-of-kvbuf (all dead by k_mid time)
    unsigned short* mid = (unsigned short*)ws; // 8,388,608 us

    k_ln<<<2048, 256, 0, stream>>>(x, ln_out_g, ln_out_b, pre);
    k_gemm<<<dim3(8, 128), 256, 0, stream>>>(pre, w_kv, nullptr, kvbuf, 512);
    k_gemm<<<dim3(1, 128), 256, 0, stream>>>(pre, w_q, nullptr, qbuf, 32);
    k_gemm<<<dim3(1, 128), 256, 0, stream>>>(x, w_down, b_down, resbuf, 32);
    k_argmax<<<dim3(16, 8, 8), 256, 0, stream>>>(qbuf, kvbuf, idxbuf);
    k_cvtT<<<dim3(16, 4), 256, 0, stream>>>(w_outer, woT, 256, 1024);
    k_cvtT<<<dim3(1, 16), 256, 0, stream>>>(w_inner, wiT, 1024, 64);
    k_hsum<<<256, 256, 0, stream>>>(kvbuf, idxbuf, resbuf, ln_rel_g, ln_rel_b, ubuf);
    k_mid<<<dim3(128, 16), 256, 0, stream>>>(ubuf, wiT, b_inner, mid);
    k_out<<<dim3(128, 4), 256, 0, stream>>>(mid, woT, b_outer, x, out);
}

// Round 5
// 164.722 us; speedup vs baseline: 1.7360x; 1.1937x over previous
//
#include <hip/hip_runtime.h>
#include <math.h>

#define D_    256
#define N_    1024
#define B_    8
#define H_    8
#define DV_   32
#define HID_  1024
#define ROWS_ (B_*N_)   // 8192

typedef _Float16 f16;
typedef __attribute__((ext_vector_type(8))) _Float16 f16x8;
typedef __attribute__((ext_vector_type(4))) _Float16 f16x4;
typedef __attribute__((ext_vector_type(8))) short s16x8;
typedef __attribute__((ext_vector_type(4))) float f32x4;

#define LO_SCALE   2048.0f          // 2^11: lifts lo plane out of f16 subnormal range
#define INV_LO     (1.0f/2048.0f)
#define INV_LO2    (1.0f/4194304.0f)

__device__ __forceinline__ unsigned short f2bf(float f) {
    unsigned u = __float_as_uint(f);
    unsigned r = (u + 0x7fffu + ((u >> 16) & 1u)) >> 16;
    return (unsigned short)r;
}

// fast erf (Abramowitz-Stegun 7.1.26, |err| < 1.5e-7)
__device__ __forceinline__ float erf_fast(float x) {
    float ax = fabsf(x);
    float t = 1.f / (1.f + 0.3275911f * ax);
    float y = ((((1.061405429f * t - 1.453152027f) * t + 1.421413741f) * t
                - 0.284496736f) * t + 0.254829592f) * t;
    float e = __expf(-ax * ax);
    float r = 1.f - y * e;
    return x < 0.f ? -r : r;
}
__device__ __forceinline__ float gelu(float v) {
    return 0.5f * v * (1.f + erf_fast(v * 0.70710678118f));
}

// ---------------------------------------------------------------- LayerNorm
__global__ __launch_bounds__(256) void k_ln(const float* __restrict__ x,
        const float* __restrict__ g, const float* __restrict__ b,
        float* __restrict__ pre) {
    int t = threadIdx.x;
    int lane = t & 63;
    int row = blockIdx.x * 4 + (t >> 6);
    const float4 v = ((const float4*)(x + row * D_))[lane];
    float s  = v.x + v.y + v.z + v.w;
    float sq = v.x*v.x + v.y*v.y + v.z*v.z + v.w*v.w;
    #pragma unroll
    for (int o = 32; o; o >>= 1) { s += __shfl_xor(s, o); sq += __shfl_xor(sq, o); }
    float m   = s * (1.0f / D_);
    float var = sq * (1.0f / D_) - m * m;
    float rs  = rsqrtf(var + 1e-5f);
    const float4 gv = ((const float4*)g)[lane];
    const float4 bv = ((const float4*)b)[lane];
    float4 o;
    o.x = (v.x - m) * rs * gv.x + bv.x;
    o.y = (v.y - m) * rs * gv.y + bv.y;
    o.z = (v.z - m) * rs * gv.z + bv.z;
    o.w = (v.w - m) * rs * gv.w + bv.w;
    ((float4*)(pre + row * D_))[lane] = o;
}

// ------------------------------------------------- generic fp32 tiled GEMM
__global__ __launch_bounds__(256) void k_gemm(const float* __restrict__ A,
        const float* __restrict__ Bm, const float* __restrict__ bias,
        float* __restrict__ C, int Ncols) {
    __shared__ float As[16][64];
    __shared__ float Bs[16][64];
    int t = threadIdx.x;
    int nBase = blockIdx.x * 64, rowBase = blockIdx.y * 64;
    int tx = t & 15, ty = t >> 4;
    int arow = t >> 2, ak = (t & 3) * 4;
    int bk = t >> 4, bn = (t & 15) * 4;
    float acc[4][4] = {};
    for (int kt = 0; kt < 256; kt += 16) {
        float4 av = *(const float4*)(A + (rowBase + arow) * 256 + kt + ak);
        As[ak+0][arow] = av.x; As[ak+1][arow] = av.y;
        As[ak+2][arow] = av.z; As[ak+3][arow] = av.w;
        float4 bv = make_float4(0.f, 0.f, 0.f, 0.f);
        if (nBase + bn < Ncols)
            bv = *(const float4*)(Bm + (kt + bk) * Ncols + nBase + bn);
        *(float4*)&Bs[bk][bn] = bv;
        __syncthreads();
        #pragma unroll
        for (int kk = 0; kk < 16; ++kk) {
            float4 a4 = *(const float4*)&As[kk][ty*4];
            float4 b4 = *(const float4*)&Bs[kk][tx*4];
            acc[0][0] += a4.x*b4.x; acc[0][1] += a4.x*b4.y; acc[0][2] += a4.x*b4.z; acc[0][3] += a4.x*b4.w;
            acc[1][0] += a4.y*b4.x; acc[1][1] += a4.y*b4.y; acc[1][2] += a4.y*b4.z; acc[1][3] += a4.y*b4.w;
            acc[2][0] += a4.z*b4.x; acc[2][1] += a4.z*b4.y; acc[2][2] += a4.z*b4.z; acc[2][3] += a4.z*b4.w;
            acc[3][0] += a4.w*b4.x; acc[3][1] += a4.w*b4.y; acc[3][2] += a4.w*b4.z; acc[3][3] += a4.w*b4.w;
        }
        __syncthreads();
    }
    int col = nBase + tx * 4;
    if (col < Ncols) {
        float4 bb = make_float4(0.f,0.f,0.f,0.f);
        if (bias) bb = *(const float4*)(bias + col);
        #pragma unroll
        for (int i = 0; i < 4; ++i) {
            float4 o;
            o.x = acc[i][0] + bb.x; o.y = acc[i][1] + bb.y;
            o.z = acc[i][2] + bb.z; o.w = acc[i][3] + bb.w;
            *(float4*)(C + (rowBase + ty*4 + i) * Ncols + col) = o;
        }
    }
}

// ------------------------------------------------- K -> fp16 hi/lo planes
// lo plane scaled by 2^11 so it stays in f16 normal range (MFMA flushes denormals)
__global__ __launch_bounds__(256) void k_cvtK(const float* __restrict__ kv,
        f16* __restrict__ khi, f16* __restrict__ klo) {
    int id = blockIdx.x * 256 + threadIdx.x;   // 0..524287
    int row = id >> 6, c4 = id & 63;
    float4 v = *(const float4*)(kv + (size_t)row * 512 + c4 * 4);
    f16 h0 = (f16)v.x, h1 = (f16)v.y, h2 = (f16)v.z, h3 = (f16)v.w;
    f16x4 hv = {h0, h1, h2, h3};
    f16x4 lv = {(f16)((v.x - (float)h0) * LO_SCALE),
                (f16)((v.y - (float)h1) * LO_SCALE),
                (f16)((v.z - (float)h2) * LO_SCALE),
                (f16)((v.w - (float)h3) * LO_SCALE)};
    *(f16x4*)(khi + (size_t)row * 256 + c4 * 4) = hv;
    *(f16x4*)(klo + (size_t)row * 256 + c4 * 4) = lv;
}

// ------------------------------------------------- scores argmax (fp16x2 MFMA)
// score = qh*kh + (qh*kl + ql*kh)/2^11 + ql*kl/2^22  (exact fp16x2 product)
__global__ __launch_bounds__(256) void k_argmax(const float* __restrict__ q,
        const f16* __restrict__ khi_g, const f16* __restrict__ klo_g,
        int* __restrict__ idx) {
    __shared__ f16x8 KH[4][128];   // [k-chunk][j] 16B units
    __shared__ f16x8 KL[4][128];
    int t = threadIdx.x;
    int itile = blockIdx.x, h = blockIdx.y, b = blockIdx.z;
    int i0 = itile * 64;
    int w = t >> 6, l = t & 63, m = l & 15, g = l >> 4;
    // Q fragment: lane holds Q[i0+w*16+m][g*8 .. g*8+7] as hi/lo(scaled) fp16
    f16x8 qh, ql;
    {
        const float* qp = q + (size_t)(b * N_ + i0 + w * 16 + m) * 32 + g * 8;
        #pragma unroll
        for (int kk = 0; kk < 8; ++kk) {
            float v = qp[kk];
            f16 hi = (f16)v;
            qh[kk] = hi;
            ql[kk] = (f16)((v - (float)hi) * LO_SCALE);
        }
    }
    int js = t >> 1, cp = t & 1;
    const uint4* gh = (const uint4*)(khi_g + (size_t)(b * N_) * 256 + h * 32);
    const uint4* gl = (const uint4*)(klo_g + (size_t)(b * N_) * 256 + h * 32);
    uint4 u0h, u1h, u0l, u1l;
    {
        int r = js * 32 + cp * 2;
        u0h = gh[r]; u1h = gh[r + 1]; u0l = gl[r]; u1l = gl[r + 1];
    }
    float best[4] = {-3e38f, -3e38f, -3e38f, -3e38f};
    int   bj[4]   = {0, 0, 0, 0};
    for (int ch = 0; ch < 8; ++ch) {
        if (ch) __syncthreads();
        *(uint4*)&KH[cp * 2    ][js] = u0h;
        *(uint4*)&KH[cp * 2 + 1][js] = u1h;
        *(uint4*)&KL[cp * 2    ][js] = u0l;
        *(uint4*)&KL[cp * 2 + 1][js] = u1l;
        __syncthreads();
        if (ch < 7) {
            int r = ((ch + 1) * 128 + js) * 32 + cp * 2;
            u0h = gh[r]; u1h = gh[r + 1]; u0l = gl[r]; u1l = gl[r + 1];
        }
        int jb = ch * 128;
        #pragma unroll
        for (int jt = 0; jt < 8; ++jt) {
            int jl = jt * 16 + m;
            f16x8 bh = KH[g][jl];
            f16x8 bl = KL[g][jl];
            f32x4 ah = {0.f, 0.f, 0.f, 0.f};
            f32x4 ax = ah, al = ah;
            ah = __builtin_amdgcn_mfma_f32_16x16x32_f16(qh, bh, ah, 0, 0, 0);
            ax = __builtin_amdgcn_mfma_f32_16x16x32_f16(qh, bl, ax, 0, 0, 0);
            ax = __builtin_amdgcn_mfma_f32_16x16x32_f16(ql, bh, ax, 0, 0, 0);
            al = __builtin_amdgcn_mfma_f32_16x16x32_f16(ql, bl, al, 0, 0, 0);
            int jg = jb + jl;
            #pragma unroll
            for (int r = 0; r < 4; ++r) {
                float s = ah[r] + ax[r] * INV_LO + al[r] * INV_LO2;
                if (s > best[r]) { best[r] = s; bj[r] = jg; }
            }
        }
    }
    // argmax reduce across the 16 j-lanes of each row group (first-max wins)
    #pragma unroll
    for (int off = 1; off < 16; off <<= 1) {
        #pragma unroll
        for (int r = 0; r < 4; ++r) {
            float ov = __shfl_xor(best[r], off);
            int   oj = __shfl_xor(bj[r], off);
            if (ov > best[r] || (ov == best[r] && oj < bj[r])) {
                best[r] = ov; bj[r] = oj;
            }
        }
    }
    if (m == 0) {
        #pragma unroll
        for (int r = 0; r < 4; ++r)
            idx[(b * H_ + h) * N_ + i0 + w * 16 + g * 4 + r] = bj[r];
    }
}

// ------------------------------------------------- gather + LN(32) + head-sum
__global__ __launch_bounds__(256) void k_hsum(const float* __restrict__ kv,
        const int* __restrict__ idx, const float* __restrict__ res,
        const float* __restrict__ g, const float* __restrict__ bb,
        unsigned short* __restrict__ u) {
    __shared__ float rel[32][8][33];
    int t = threadIdx.x;
    int rowBase = blockIdx.x * 32;
    int rw = t >> 3, h = t & 7;
    int bn = rowBase + rw;
    int b = bn >> 10, i = bn & 1023;
    int j = idx[(b * H_ + h) * N_ + i];
    const float4* src = (const float4*)kv + (b * N_ + j) * 128 + 64 + h * 8;
    float v[32];
    #pragma unroll
    for (int c = 0; c < 8; ++c) {
        float4 f = src[c];
        v[c*4+0] = f.x; v[c*4+1] = f.y; v[c*4+2] = f.z; v[c*4+3] = f.w;
    }
    float s = 0.f, sq = 0.f;
    #pragma unroll
    for (int d = 0; d < 32; ++d) { s += v[d]; sq += v[d]*v[d]; }
    float m = s * (1.f/32.f), var = sq * (1.f/32.f) - m * m;
    float rs = rsqrtf(var + 1e-5f);
    #pragma unroll
    for (int d = 0; d < 32; ++d)
        rel[rw][h][d] = (v[d] - m) * rs * g[d] + bb[d];
    __syncthreads();
    #pragma unroll
    for (int e = t; e < 1024; e += 256) {
        int r = e >> 5, d = e & 31;
        float acc = 0.f;
        #pragma unroll
        for (int hh = 0; hh < 8; ++hh) acc += rel[r][hh][d];
        u[(rowBase + r) * 64 + d]      = f2bf(acc);
        u[(rowBase + r) * 64 + 32 + d] = f2bf(8.f * res[(rowBase + r) * 32 + d]);
    }
}

// ------------------------------------------------- transpose + bf16 convert
__global__ __launch_bounds__(256) void k_cvtT(const float* __restrict__ src,
        unsigned short* __restrict__ dst, int srcCols, int dstCols) {
    __shared__ float t64[64][65];
    int t = threadIdx.x;
    int r0 = blockIdx.x * 64, c0 = blockIdx.y * 64;
    #pragma unroll
    for (int e = t; e < 4096; e += 256) {
        int r = e >> 6, c = e & 63;
        t64[r][c] = src[(size_t)(r0 + r) * srcCols + c0 + c];
    }
    __syncthreads();
    #pragma unroll
    for (int e = t; e < 4096; e += 256) {
        int c = e >> 6, r = e & 63;
        dst[(size_t)(c0 + c) * dstCols + r0 + r] = f2bf(t64[r][c]);
    }
}

// ------------------------------------------------- mid = gelu(u @ w_inner + 8*b_inner)
__global__ __launch_bounds__(256) void k_mid(const unsigned short* __restrict__ u,
        const unsigned short* __restrict__ wiT, const float* __restrict__ b_inner,
        unsigned short* __restrict__ mid) {
    __shared__ __align__(16) unsigned short As[4096];
    __shared__ __align__(16) unsigned short Bs[4096];
    int t = threadIdx.x;
    int rowBase = blockIdx.x * 64, colBase = blockIdx.y * 64;
    int l = t & 63, w = t >> 6, wr = w >> 1, wc = w & 1;
    int r = t >> 2, cA = (t & 3) * 2;
    {
        uint4 a0 = *(const uint4*)(u   + (size_t)(rowBase + r) * 64 + cA * 8);
        uint4 a1 = *(const uint4*)(u   + (size_t)(rowBase + r) * 64 + cA * 8 + 8);
        uint4 b0 = *(const uint4*)(wiT + (size_t)(colBase + r) * 64 + cA * 8);
        uint4 b1 = *(const uint4*)(wiT + (size_t)(colBase + r) * 64 + cA * 8 + 8);
        *(uint4*)&As[(r * 8 + ( cA      ^ (r & 7))) * 8] = a0;
        *(uint4*)&As[(r * 8 + ((cA + 1) ^ (r & 7))) * 8] = a1;
        *(uint4*)&Bs[(r * 8 + ( cA      ^ (r & 7))) * 8] = b0;
        *(uint4*)&Bs[(r * 8 + ((cA + 1) ^ (r & 7))) * 8] = b1;
    }
    __syncthreads();
    f32x4 acc00 = {0.f,0.f,0.f,0.f}, acc01 = acc00, acc10 = acc00, acc11 = acc00;
    int m = l & 15, g = l >> 4;
    int swm = m & 7;
    #pragma unroll
    for (int ks = 0; ks < 2; ++ks) {
        int kc = ks * 4 + g;
        int sc = kc ^ swm;
        s16x8 a0 = *(const s16x8*)&As[((wr*32      + m) * 8 + sc) * 8];
        s16x8 a1 = *(const s16x8*)&As[((wr*32 + 16 + m) * 8 + sc) * 8];
        s16x8 b0 = *(const s16x8*)&Bs[((wc*32      + m) * 8 + sc) * 8];
        s16x8 b1 = *(const s16x8*)&Bs[((wc*32 + 16 + m) * 8 + sc) * 8];
        acc00 = __builtin_amdgcn_mfma_f32_16x16x32_bf16(a0, b0, acc00, 0, 0, 0);
        acc01 = __builtin_amdgcn_mfma_f32_16x16x32_bf16(a0, b1, acc01, 0, 0, 0);
        acc10 = __builtin_amdgcn_mfma_f32_16x16x32_bf16(a1, b0, acc10, 0, 0, 0);
        acc11 = __builtin_amdgcn_mfma_f32_16x16x32_bf16(a1, b1, acc11, 0, 0, 0);
    }
    #pragma unroll
    for (int fr = 0; fr < 2; ++fr) {
        #pragma unroll
        for (int fc = 0; fc < 2; ++fc) {
            f32x4 A = fr == 0 ? (fc == 0 ? acc00 : acc01)
                              : (fc == 0 ? acc10 : acc11);
            int col = colBase + wc * 32 + fc * 16 + m;
            float bi = 8.f * b_inner[col];
            #pragma unroll
            for (int rr = 0; rr < 4; ++rr) {
                int row = rowBase + wr * 32 + fr * 16 + g * 4 + rr;
                mid[(size_t)row * HID_ + col] = f2bf(gelu(A[rr] + bi));
            }
        }
    }
}

// ------------------------------------------------- out = mid @ w_outer + b_outer + x
__global__ __launch_bounds__(256) void k_out(const unsigned short* __restrict__ mid,
        const unsigned short* __restrict__ woT, const float* __restrict__ b_outer,
        const float* __restrict__ x, float* __restrict__ out) {
    __shared__ __align__(16) unsigned short As[2][4096];
    __shared__ __align__(16) unsigned short Bs[2][4096];
    int t = threadIdx.x;
    int rowBase = blockIdx.x * 64, colBase = blockIdx.y * 64;
    int l = t & 63, w = t >> 6, wr = w >> 1, wc = w & 1;
    int r0 = t >> 3,        c0 = t & 7;
    int r1 = (t + 256) >> 3, c1 = t & 7;
    int s0 = (r0 * 8 + (c0 ^ (r0 & 7))) * 8;
    int s1 = (r1 * 8 + (c1 ^ (r1 & 7))) * 8;
    f32x4 acc00 = {0.f,0.f,0.f,0.f}, acc01 = acc00, acc10 = acc00, acc11 = acc00;
    int m = l & 15, g = l >> 4;
    int swm = m & 7;
    {
        uint4 va0 = *(const uint4*)(mid + (size_t)(rowBase + r0) * 1024 + c0 * 8);
        uint4 va1 = *(const uint4*)(mid + (size_t)(rowBase + r1) * 1024 + c1 * 8);
        uint4 vb0 = *(const uint4*)(woT + (size_t)(colBase + r0) * 1024 + c0 * 8);
        uint4 vb1 = *(const uint4*)(woT + (size_t)(colBase + r1) * 1024 + c1 * 8);
        *(uint4*)&As[0][s0] = va0; *(uint4*)&As[0][s1] = va1;
        *(uint4*)&Bs[0][s0] = vb0; *(uint4*)&Bs[0][s1] = vb1;
    }
    __syncthreads();
    int cur = 0;
    for (int kt = 0; kt < 16; ++kt) {
        uint4 va0, va1, vb0, vb1;
        bool pf = (kt + 1) < 16;
        if (pf) {
            int k0 = (kt + 1) * 64;
            va0 = *(const uint4*)(mid + (size_t)(rowBase + r0) * 1024 + k0 + c0 * 8);
            va1 = *(const uint4*)(mid + (size_t)(rowBase + r1) * 1024 + k0 + c1 * 8);
            vb0 = *(const uint4*)(woT + (size_t)(colBase + r0) * 1024 + k0 + c0 * 8);
            vb1 = *(const uint4*)(woT + (size_t)(colBase + r1) * 1024 + k0 + c1 * 8);
        }
        #pragma unroll
        for (int ks = 0; ks < 2; ++ks) {
            int kc = ks * 4 + g;
            int sc = kc ^ swm;
            s16x8 a0 = *(const s16x8*)&As[cur][((wr*32      + m) * 8 + sc) * 8];
            s16x8 a1 = *(const s16x8*)&As[cur][((wr*32 + 16 + m) * 8 + sc) * 8];
            s16x8 b0 = *(const s16x8*)&Bs[cur][((wc*32      + m) * 8 + sc) * 8];
            s16x8 b1 = *(const s16x8*)&Bs[cur][((wc*32 + 16 + m) * 8 + sc) * 8];
            acc00 = __builtin_amdgcn_mfma_f32_16x16x32_bf16(a0, b0, acc00, 0, 0, 0);
            acc01 = __builtin_amdgcn_mfma_f32_16x16x32_bf16(a0, b1, acc01, 0, 0, 0);
            acc10 = __builtin_amdgcn_mfma_f32_16x16x32_bf16(a1, b0, acc10, 0, 0, 0);
            acc11 = __builtin_amdgcn_mfma_f32_16x16x32_bf16(a1, b1, acc11, 0, 0, 0);
        }
        if (pf) {
            *(uint4*)&As[cur ^ 1][s0] = va0; *(uint4*)&As[cur ^ 1][s1] = va1;
            *(uint4*)&Bs[cur ^ 1][s0] = vb0; *(uint4*)&Bs[cur ^ 1][s1] = vb1;
        }
        __syncthreads();
        cur ^= 1;
    }
    #pragma unroll
    for (int fr = 0; fr < 2; ++fr) {
        #pragma unroll
        for (int fc = 0; fc < 2; ++fc) {
            f32x4 A = fr == 0 ? (fc == 0 ? acc00 : acc01)
                              : (fc == 0 ? acc10 : acc11);
            int col = colBase + wc * 32 + fc * 16 + m;
            float bo = b_outer[col];
            #pragma unroll
            for (int rr = 0; rr < 4; ++rr) {
                int row = rowBase + wr * 32 + fr * 16 + g * 4 + rr;
                out[(size_t)row * 256 + col] = A[rr] + bo + x[(size_t)row * 256 + col];
            }
        }
    }
}

extern "C" void kernel_launch(void* const* d_in, const int* in_sizes, int n_in,
                              void* d_out, int out_size, void* d_ws, size_t ws_size,
                              hipStream_t stream) {
    const float* x        = (const float*)d_in[0];
    const float* w_q      = (const float*)d_in[1];
    const float* w_kv     = (const float*)d_in[2];
    const float* ln_out_g = (const float*)d_in[3];
    const float* ln_out_b = (const float*)d_in[4];
    const float* ln_rel_g = (const float*)d_in[5];
    const float* ln_rel_b = (const float*)d_in[6];
    const float* w_down   = (const float*)d_in[7];
    const float* b_down   = (const float*)d_in[8];
    const float* w_inner  = (const float*)d_in[9];
    const float* b_inner  = (const float*)d_in[10];
    const float* w_outer  = (const float*)d_in[11];
    const float* b_outer  = (const float*)d_in[12];
    float* out = (float*)d_out;

    float* ws     = (float*)d_ws;
    float* pre    = ws;                        // 2,097,152 f (dead after q/kv gemms)
    float* qbuf   = ws + 2097152;              //   262,144 f
    float* kvbuf  = ws + 2359296;              // 4,194,304 f -> 6,553,600
    float* resbuf = ws + 6553600;              //   262,144 f -> 6,815,744
    unsigned short* ubuf = (unsigned short*)(ws + 6815744);  // 524,288 us -> 7,077,888
    int*   idxbuf = (int*)(ws + 7077888);      //    65,536 i -> 7,143,424
    unsigned short* woT = (unsigned short*)(ws + 7143424);   // 262,144 us -> 7,274,496
    unsigned short* wiT = (unsigned short*)(ws + 7274496);   //  65,536 us -> 7,307,264
    // khi/klo alias dead `pre` (8 MB): 2×[8192*256] f16
    f16* khi = (f16*)ws;
    f16* klo = khi + 2097152;
    // mid aliases ws start (khi/klo dead after argmax)
    unsigned short* mid = (unsigned short*)ws;

    k_ln<<<2048, 256, 0, stream>>>(x, ln_out_g, ln_out_b, pre);
    k_gemm<<<dim3(8, 128), 256, 0, stream>>>(pre, w_kv, nullptr, kvbuf, 512);
    k_gemm<<<dim3(1, 128), 256, 0, stream>>>(pre, w_q, nullptr, qbuf, 32);
    k_gemm<<<dim3(1, 128), 256, 0, stream>>>(x, w_down, b_down, resbuf, 32);
    k_cvtK<<<2048, 256, 0, stream>>>(kvbuf, khi, klo);
    k_argmax<<<dim3(16, 8, 8), 256, 0, stream>>>(qbuf, khi, klo, idxbuf);
    k_cvtT<<<dim3(16, 4), 256, 0, stream>>>(w_outer, woT, 256, 1024);
    k_cvtT<<<dim3(1, 16), 256, 0, stream>>>(w_inner, wiT, 1024, 64);
    k_hsum<<<256, 256, 0, stream>>>(kvbuf, idxbuf, resbuf, ln_rel_g, ln_rel_b, ubuf);
    k_mid<<<dim3(128, 16), 256, 0, stream>>>(ubuf, wiT, b_inner, mid);
    k_out<<<dim3(128, 4), 256, 0, stream>>>(mid, woT, b_outer, x, out);
}